// Round 1
// baseline (191.019 us; speedup 1.0000x reference)
//
#include <hip/hip_runtime.h>
#include <math.h>

// Problem constants (match reference module constants)
constexpr int D_MODEL  = 256;
constexpr int N_HEADS  = 8;
constexpr int N_LEVELS = 4;
constexpr int N_POINTS = 4;
constexpr int HEAD_DIM = 32;

__device__ __constant__ int c_H[4]     = {96, 48, 24, 12};
__device__ __constant__ int c_W[4]     = {96, 48, 24, 12};
__device__ __constant__ int c_start[4] = {0, 9216, 11520, 12096};

// ---------------------------------------------------------------------------
// Tiled f32 GEMM: C[M,N] = A[M,256] * B[256,N] (+ bias), with fused epilogues.
// OFFATTN=true : B is split {W_off (cols 0..255, ld=256) | W_attn (cols 256..383, ld=128)}
//                epilogue: loc = ref + (off+b)/norm  -> out0[q*256 + c]
//                          attn = softmax16(score+b) -> out1[q*128 + c']
// OFFATTN=false: B = W_out (ld=256); epilogue: out0 = acc + b_out
// Tile: BM=64, BN=64, BK=16; 256 threads, each computes 4x4.
// ---------------------------------------------------------------------------
template <bool OFFATTN>
__global__ __launch_bounds__(256) void gemm_fused(
    const float* __restrict__ A,
    const float* __restrict__ Wa,
    const float* __restrict__ Wb,
    const float* __restrict__ ba,
    const float* __restrict__ bb,
    const float* __restrict__ refpts,
    float* __restrict__ out0,
    float* __restrict__ out1,
    int M)
{
    __shared__ float As[16][64];
    __shared__ float Bs[16][64];

    const int tid = threadIdx.x;
    const int m0  = blockIdx.y * 64;
    const int n0  = blockIdx.x * 64;

    // A-stage indices: thread reads 4 consecutive k of one row
    const int ai = tid >> 2;          // 0..63 (row in tile)
    const int aj = (tid & 3) * 4;     // 0,4,8,12 (k offset)
    // B-stage indices: thread reads 4 consecutive cols of one k-row
    const int bi = tid >> 4;          // 0..15 (k row)
    const int bj = (tid & 15) * 4;    // 0..60 (col offset)

    // Resolve weight pointer for this block's column range (uniform per block)
    const float* Bptr;
    int ldb, coff;
    if (OFFATTN && n0 >= 256) { Bptr = Wb; ldb = 128; coff = n0 - 256; }
    else                      { Bptr = Wa; ldb = 256; coff = n0; }

    const int tm = (tid >> 4) * 4;    // output row base 0..60
    const int tn = (tid & 15) * 4;    // output col base 0..60

    float acc[4][4] = {};

    for (int k0 = 0; k0 < 256; k0 += 16) {
        float4 av = make_float4(0.f, 0.f, 0.f, 0.f);
        if (m0 + ai < M)
            av = *reinterpret_cast<const float4*>(&A[(size_t)(m0 + ai) * 256 + k0 + aj]);
        As[aj + 0][ai] = av.x;
        As[aj + 1][ai] = av.y;
        As[aj + 2][ai] = av.z;
        As[aj + 3][ai] = av.w;

        float4 bv = *reinterpret_cast<const float4*>(&Bptr[(size_t)(k0 + bi) * ldb + coff + bj]);
        *reinterpret_cast<float4*>(&Bs[bi][bj]) = bv;

        __syncthreads();
#pragma unroll
        for (int kk = 0; kk < 16; ++kk) {
            float4 a4 = *reinterpret_cast<const float4*>(&As[kk][tm]);
            float4 b4 = *reinterpret_cast<const float4*>(&Bs[kk][tn]);
            float av_[4] = {a4.x, a4.y, a4.z, a4.w};
            float bv_[4] = {b4.x, b4.y, b4.z, b4.w};
#pragma unroll
            for (int i = 0; i < 4; ++i)
#pragma unroll
                for (int j = 0; j < 4; ++j)
                    acc[i][j] = fmaf(av_[i], bv_[j], acc[i][j]);
        }
        __syncthreads();
    }

    if constexpr (!OFFATTN) {
        // out = acc + b_out
#pragma unroll
        for (int i = 0; i < 4; ++i) {
            int q = m0 + tm + i;
            if (q >= M) continue;
            float4 v;
            v.x = acc[i][0] + ba[n0 + tn + 0];
            v.y = acc[i][1] + ba[n0 + tn + 1];
            v.z = acc[i][2] + ba[n0 + tn + 2];
            v.w = acc[i][3] + ba[n0 + tn + 3];
            *reinterpret_cast<float4*>(&out0[(size_t)q * 256 + n0 + tn]) = v;
        }
    } else {
        if (n0 < 256) {
            // off columns -> sampling locations
#pragma unroll
            for (int i = 0; i < 4; ++i) {
                int q = m0 + tm + i;
                if (q >= M) continue;
                float rx = refpts[q * 2 + 0];
                float ry = refpts[q * 2 + 1];
                float tmp[4];
#pragma unroll
                for (int j = 0; j < 4; ++j) {
                    int c = n0 + tn + j;          // c = h*32 + l*8 + p*2 + xy
                    float val = acc[i][j] + ba[c];
                    int xy = c & 1;
                    int l  = (c >> 3) & 3;
                    float norm = xy ? (float)c_H[l] : (float)c_W[l];
                    tmp[j] = (xy ? ry : rx) + val / norm;
                }
                float4 v = make_float4(tmp[0], tmp[1], tmp[2], tmp[3]);
                *reinterpret_cast<float4*>(&out0[(size_t)q * 256 + n0 + tn]) = v;
            }
        } else {
            // attn columns -> softmax over 16 per (q, h)
            __shared__ float Stile[64][65];
#pragma unroll
            for (int i = 0; i < 4; ++i)
#pragma unroll
                for (int j = 0; j < 4; ++j) {
                    int c = n0 + tn + j - 256;
                    Stile[tm + i][tn + j] = acc[i][j] + bb[c];
                }
            __syncthreads();

            int ql = tid & 63;
            int hh = tid >> 6;                 // 0..3 (head-group in this tile)
            int q  = m0 + ql;
            if (q < M) {
                float s[16];
                float mx = -1e30f;
#pragma unroll
                for (int i = 0; i < 16; ++i) {
                    s[i] = Stile[ql][hh * 16 + i];
                    mx = fmaxf(mx, s[i]);
                }
                float sum = 0.f;
#pragma unroll
                for (int i = 0; i < 16; ++i) {
                    s[i] = __expf(s[i] - mx);
                    sum += s[i];
                }
                float inv = 1.0f / sum;
                int cbase = (n0 - 256) + hh * 16;   // = h*16
#pragma unroll
                for (int i = 0; i < 16; ++i)
                    out1[(size_t)q * 128 + cbase + i] = s[i] * inv;
            }
        }
    }
}

// ---------------------------------------------------------------------------
// Deformable bilinear sampling.
// One 32-lane group per (q, h); lane = head dim d. 16 points x 4 corners.
// core[q*256 + h*32 + d] = sum_{l,p} attn * bilinear(value, loc)
// ---------------------------------------------------------------------------
__global__ __launch_bounds__(256) void sample_kernel(
    const float* __restrict__ loc,
    const float* __restrict__ attn,
    const float* __restrict__ value,   // input_flatten, [Len, 256]
    float* __restrict__ core,
    int M)
{
    const int unit = blockIdx.x * 8 + (threadIdx.x >> 5);
    const int d    = threadIdx.x & 31;
    const int q    = unit >> 3;
    const int h    = unit & 7;
    if (q >= M) return;

    const float* locq = loc  + (size_t)q * 256 + h * 32;
    const float* attq = attn + (size_t)q * 128 + h * 16;

    float acc = 0.f;
#pragma unroll
    for (int l = 0; l < 4; ++l) {
        const int Wl = c_W[l];
        const int Hl = c_H[l];
        const float fW = (float)Wl;
        const float fH = (float)Hl;
        const float* feat = value + ((size_t)c_start[l]) * 256 + h * 32 + d;
#pragma unroll
        for (int p = 0; p < 4; ++p) {
            float lx = locq[l * 8 + p * 2 + 0];
            float ly = locq[l * 8 + p * 2 + 1];
            float w  = attq[l * 4 + p];

            float x = lx * fW - 0.5f;
            float y = ly * fH - 0.5f;
            float x0f = floorf(x);
            float y0f = floorf(y);
            float wx1 = x - x0f, wy1 = y - y0f;
            float wx0 = 1.f - wx1, wy0 = 1.f - wy1;
            int ix = (int)x0f;
            int iy = (int)y0f;

            float v00 = 0.f, v10 = 0.f, v01 = 0.f, v11 = 0.f;
            bool xin0 = (unsigned)ix       < (unsigned)Wl;
            bool xin1 = (unsigned)(ix + 1) < (unsigned)Wl;
            bool yin0 = (unsigned)iy       < (unsigned)Hl;
            bool yin1 = (unsigned)(iy + 1) < (unsigned)Hl;
            if (yin0) {
                const float* row = feat + (size_t)iy * Wl * 256;
                if (xin0) v00 = row[(size_t)ix * 256];
                if (xin1) v10 = row[(size_t)(ix + 1) * 256];
            }
            if (yin1) {
                const float* row = feat + (size_t)(iy + 1) * Wl * 256;
                if (xin0) v01 = row[(size_t)ix * 256];
                if (xin1) v11 = row[(size_t)(ix + 1) * 256];
            }
            float bil = v00 * (wx0 * wy0) + v10 * (wx1 * wy0)
                      + v01 * (wx0 * wy1) + v11 * (wx1 * wy1);
            acc = fmaf(w, bil, acc);
        }
    }
    core[(size_t)q * 256 + h * 32 + d] = acc;
}

// ---------------------------------------------------------------------------
extern "C" void kernel_launch(void* const* d_in, const int* in_sizes, int n_in,
                              void* d_out, int out_size, void* d_ws, size_t ws_size,
                              hipStream_t stream)
{
    const float* query  = (const float*)d_in[0];
    const float* refp   = (const float*)d_in[1];
    const float* value  = (const float*)d_in[2];
    // d_in[3] spatial_shapes, d_in[4] level_start_index: compile-time constants
    const float* W_off  = (const float*)d_in[5];
    const float* b_off  = (const float*)d_in[6];
    const float* W_attn = (const float*)d_in[7];
    const float* b_attn = (const float*)d_in[8];
    const float* W_out  = (const float*)d_in[9];
    const float* b_out  = (const float*)d_in[10];
    float* out = (float*)d_out;

    const int M = in_sizes[0] / D_MODEL;   // 12240

    float* loc  = (float*)d_ws;                      // M*256 floats
    float* attn = loc  + (size_t)M * 256;            // M*128 floats
    float* core = attn + (size_t)M * 128;            // M*256 floats

    dim3 blk(256);

    // Stage 1: fused offsets/attention GEMM + loc/softmax epilogue
    dim3 g1(6, (M + 63) / 64);
    hipLaunchKernelGGL((gemm_fused<true>), g1, blk, 0, stream,
                       query, W_off, W_attn, b_off, b_attn, refp, loc, attn, M);

    // Stage 2: deformable bilinear sampling
    dim3 g2((M * 8 + 7) / 8);
    hipLaunchKernelGGL(sample_kernel, g2, blk, 0, stream, loc, attn, value, core, M);

    // Stage 3: output projection
    dim3 g3(4, (M + 63) / 64);
    hipLaunchKernelGGL((gemm_fused<false>), g3, blk, 0, stream,
                       core, W_out, nullptr, b_out, nullptr, nullptr, out, nullptr, M);
}

// Round 2
// 144.490 us; speedup vs baseline: 1.3220x; 1.3220x over previous
//
#include <hip/hip_runtime.h>
#include <math.h>

// Problem constants (match reference module constants)
constexpr int D_MODEL  = 256;
constexpr int N_HEADS  = 8;
constexpr int N_LEVELS = 4;
constexpr int N_POINTS = 4;
constexpr int HEAD_DIM = 32;

__device__ __constant__ int c_H[4]     = {96, 48, 24, 12};
__device__ __constant__ int c_W[4]     = {96, 48, 24, 12};
__device__ __constant__ int c_start[4] = {0, 9216, 11520, 12096};

// ---------------------------------------------------------------------------
// Tiled f32 GEMM: C[M,N] = A[M,256] * B[256,N] (+ bias), with fused epilogues.
// OFFATTN=true : B is split {W_off (cols 0..255, ld=256) | W_attn (cols 256..383, ld=128)}
//                epilogue: loc = ref + (off+b)/norm  -> out0[q*256 + c]
//                          attn = softmax16(score+b) -> out1[q*128 + c']
// OFFATTN=false: B = W_out (ld=256); epilogue: out0 = acc + b_out
// Tile: BM=64, BN=64, BK=16; 256 threads, each computes 4x4.
// ---------------------------------------------------------------------------
template <bool OFFATTN>
__global__ __launch_bounds__(256) void gemm_fused(
    const float* __restrict__ A,
    const float* __restrict__ Wa,
    const float* __restrict__ Wb,
    const float* __restrict__ ba,
    const float* __restrict__ bb,
    const float* __restrict__ refpts,
    float* __restrict__ out0,
    float* __restrict__ out1,
    int M)
{
    __shared__ float As[16][64];
    __shared__ float Bs[16][64];

    const int tid = threadIdx.x;
    const int m0  = blockIdx.y * 64;
    const int n0  = blockIdx.x * 64;

    const int ai = tid >> 2;          // 0..63 (row in tile)
    const int aj = (tid & 3) * 4;     // 0,4,8,12 (k offset)
    const int bi = tid >> 4;          // 0..15 (k row)
    const int bj = (tid & 15) * 4;    // 0..60 (col offset)

    const float* Bptr;
    int ldb, coff;
    if (OFFATTN && n0 >= 256) { Bptr = Wb; ldb = 128; coff = n0 - 256; }
    else                      { Bptr = Wa; ldb = 256; coff = n0; }

    const int tm = (tid >> 4) * 4;    // output row base 0..60
    const int tn = (tid & 15) * 4;    // output col base 0..60

    float acc[4][4] = {};

    for (int k0 = 0; k0 < 256; k0 += 16) {
        float4 av = make_float4(0.f, 0.f, 0.f, 0.f);
        if (m0 + ai < M)
            av = *reinterpret_cast<const float4*>(&A[(size_t)(m0 + ai) * 256 + k0 + aj]);
        As[aj + 0][ai] = av.x;
        As[aj + 1][ai] = av.y;
        As[aj + 2][ai] = av.z;
        As[aj + 3][ai] = av.w;

        float4 bv = *reinterpret_cast<const float4*>(&Bptr[(size_t)(k0 + bi) * ldb + coff + bj]);
        *reinterpret_cast<float4*>(&Bs[bi][bj]) = bv;

        __syncthreads();
#pragma unroll
        for (int kk = 0; kk < 16; ++kk) {
            float4 a4 = *reinterpret_cast<const float4*>(&As[kk][tm]);
            float4 b4 = *reinterpret_cast<const float4*>(&Bs[kk][tn]);
            float av_[4] = {a4.x, a4.y, a4.z, a4.w};
            float bv_[4] = {b4.x, b4.y, b4.z, b4.w};
#pragma unroll
            for (int i = 0; i < 4; ++i)
#pragma unroll
                for (int j = 0; j < 4; ++j)
                    acc[i][j] = fmaf(av_[i], bv_[j], acc[i][j]);
        }
        __syncthreads();
    }

    if constexpr (!OFFATTN) {
#pragma unroll
        for (int i = 0; i < 4; ++i) {
            int q = m0 + tm + i;
            if (q >= M) continue;
            float4 v;
            v.x = acc[i][0] + ba[n0 + tn + 0];
            v.y = acc[i][1] + ba[n0 + tn + 1];
            v.z = acc[i][2] + ba[n0 + tn + 2];
            v.w = acc[i][3] + ba[n0 + tn + 3];
            *reinterpret_cast<float4*>(&out0[(size_t)q * 256 + n0 + tn]) = v;
        }
    } else {
        if (n0 < 256) {
#pragma unroll
            for (int i = 0; i < 4; ++i) {
                int q = m0 + tm + i;
                if (q >= M) continue;
                float rx = refpts[q * 2 + 0];
                float ry = refpts[q * 2 + 1];
                float tmp[4];
#pragma unroll
                for (int j = 0; j < 4; ++j) {
                    int c = n0 + tn + j;          // c = h*32 + l*8 + p*2 + xy
                    float val = acc[i][j] + ba[c];
                    int xy = c & 1;
                    int l  = (c >> 3) & 3;
                    float norm = xy ? (float)c_H[l] : (float)c_W[l];
                    tmp[j] = (xy ? ry : rx) + val / norm;
                }
                float4 v = make_float4(tmp[0], tmp[1], tmp[2], tmp[3]);
                *reinterpret_cast<float4*>(&out0[(size_t)q * 256 + n0 + tn]) = v;
            }
        } else {
            __shared__ float Stile[64][65];
#pragma unroll
            for (int i = 0; i < 4; ++i)
#pragma unroll
                for (int j = 0; j < 4; ++j) {
                    int c = n0 + tn + j - 256;
                    Stile[tm + i][tn + j] = acc[i][j] + bb[c];
                }
            __syncthreads();

            int ql = tid & 63;
            int hh = tid >> 6;
            int q  = m0 + ql;
            if (q < M) {
                float s[16];
                float mx = -1e30f;
#pragma unroll
                for (int i = 0; i < 16; ++i) {
                    s[i] = Stile[ql][hh * 16 + i];
                    mx = fmaxf(mx, s[i]);
                }
                float sum = 0.f;
#pragma unroll
                for (int i = 0; i < 16; ++i) {
                    s[i] = __expf(s[i] - mx);
                    sum += s[i];
                }
                float inv = 1.0f / sum;
                int cbase = (n0 - 256) + hh * 16;
#pragma unroll
                for (int i = 0; i < 16; ++i)
                    out1[(size_t)q * 128 + cbase + i] = s[i] * inv;
            }
        }
    }
}

// ---------------------------------------------------------------------------
// Deformable bilinear sampling, float4-vectorized over dims.
// 8 lanes per (q,h) unit; lane owns 4 dims (float4). 16 points x 4 corners,
// each corner load = float4 (8 lanes x 16B = 128B contiguous per corner).
// ---------------------------------------------------------------------------
__global__ __launch_bounds__(256) void sample_kernel(
    const float* __restrict__ loc,
    const float* __restrict__ attn,
    const float* __restrict__ value,   // input_flatten, [Len, 256]
    float* __restrict__ core,
    int M)
{
    const int unit = blockIdx.x * 32 + (threadIdx.x >> 3);  // (q,h)
    const int d4   = threadIdx.x & 7;                        // float4 slot 0..7
    const int q    = unit >> 3;
    const int h    = unit & 7;
    if (q >= M) return;

    const float4* locq4 = reinterpret_cast<const float4*>(loc  + (size_t)q * 256 + h * 32);
    const float4* attq4 = reinterpret_cast<const float4*>(attn + (size_t)q * 128 + h * 16);

    float4 acc = make_float4(0.f, 0.f, 0.f, 0.f);

#pragma unroll
    for (int l = 0; l < 4; ++l) {
        const int Wl = c_W[l];
        const int Hl = c_H[l];
        const float fW = (float)Wl;
        const float fH = (float)Hl;
        const int rowstride = Wl * 256;
        const float* feat = value + ((size_t)c_start[l]) * 256 + h * 32 + d4 * 4;

        float4 lp0 = locq4[l * 2 + 0];   // p0.x p0.y p1.x p1.y
        float4 lp1 = locq4[l * 2 + 1];   // p2.x p2.y p3.x p3.y
        float4 aw  = attq4[l];           // w0 w1 w2 w3

        const float lxs[4] = {lp0.x, lp0.z, lp1.x, lp1.z};
        const float lys[4] = {lp0.y, lp0.w, lp1.y, lp1.w};
        const float aws[4] = {aw.x, aw.y, aw.z, aw.w};

#pragma unroll
        for (int p = 0; p < 4; ++p) {
            float x = lxs[p] * fW - 0.5f;
            float y = lys[p] * fH - 0.5f;
            float w = aws[p];

            float x0f = floorf(x);
            float y0f = floorf(y);
            float wx1 = x - x0f, wy1 = y - y0f;
            float wx0 = 1.f - wx1, wy0 = 1.f - wy1;
            int ix = (int)x0f;
            int iy = (int)y0f;

            bool xin0 = (unsigned)ix       < (unsigned)Wl;
            bool xin1 = (unsigned)(ix + 1) < (unsigned)Wl;
            bool yin0 = (unsigned)iy       < (unsigned)Hl;
            bool yin1 = (unsigned)(iy + 1) < (unsigned)Hl;

            float4 v00 = make_float4(0.f,0.f,0.f,0.f), v10 = v00, v01 = v00, v11 = v00;
            if (yin0) {
                const float* row = feat + (size_t)iy * rowstride;
                if (xin0) v00 = *reinterpret_cast<const float4*>(&row[(size_t)ix * 256]);
                if (xin1) v10 = *reinterpret_cast<const float4*>(&row[(size_t)(ix + 1) * 256]);
            }
            if (yin1) {
                const float* row = feat + (size_t)(iy + 1) * rowstride;
                if (xin0) v01 = *reinterpret_cast<const float4*>(&row[(size_t)ix * 256]);
                if (xin1) v11 = *reinterpret_cast<const float4*>(&row[(size_t)(ix + 1) * 256]);
            }

            float w00 = wx0 * wy0, w10 = wx1 * wy0, w01 = wx0 * wy1, w11 = wx1 * wy1;
            float4 bil;
            bil.x = v00.x * w00 + v10.x * w10 + v01.x * w01 + v11.x * w11;
            bil.y = v00.y * w00 + v10.y * w10 + v01.y * w01 + v11.y * w11;
            bil.z = v00.z * w00 + v10.z * w10 + v01.z * w01 + v11.z * w11;
            bil.w = v00.w * w00 + v10.w * w10 + v01.w * w01 + v11.w * w11;

            acc.x = fmaf(w, bil.x, acc.x);
            acc.y = fmaf(w, bil.y, acc.y);
            acc.z = fmaf(w, bil.z, acc.z);
            acc.w = fmaf(w, bil.w, acc.w);
        }
    }
    *reinterpret_cast<float4*>(&core[(size_t)q * 256 + h * 32 + d4 * 4]) = acc;
}

// ---------------------------------------------------------------------------
extern "C" void kernel_launch(void* const* d_in, const int* in_sizes, int n_in,
                              void* d_out, int out_size, void* d_ws, size_t ws_size,
                              hipStream_t stream)
{
    const float* query  = (const float*)d_in[0];
    const float* refp   = (const float*)d_in[1];
    const float* value  = (const float*)d_in[2];
    const float* W_off  = (const float*)d_in[5];
    const float* b_off  = (const float*)d_in[6];
    const float* W_attn = (const float*)d_in[7];
    const float* b_attn = (const float*)d_in[8];
    const float* W_out  = (const float*)d_in[9];
    const float* b_out  = (const float*)d_in[10];
    float* out = (float*)d_out;

    const int M = in_sizes[0] / D_MODEL;   // 12240

    float* loc  = (float*)d_ws;                      // M*256 floats
    float* attn = loc  + (size_t)M * 256;            // M*128 floats
    float* core = attn + (size_t)M * 128;            // M*256 floats

    dim3 blk(256);

    dim3 g1(6, (M + 63) / 64);
    hipLaunchKernelGGL((gemm_fused<true>), g1, blk, 0, stream,
                       query, W_off, W_attn, b_off, b_attn, refp, loc, attn, M);

    const int units = M * N_HEADS;
    dim3 g2((units + 31) / 32);
    hipLaunchKernelGGL(sample_kernel, g2, blk, 0, stream, loc, attn, value, core, M);

    dim3 g3(4, (M + 63) / 64);
    hipLaunchKernelGGL((gemm_fused<false>), g3, blk, 0, stream,
                       core, W_out, nullptr, b_out, nullptr, nullptr, out, nullptr, M);
}

// Round 3
// 112.094 us; speedup vs baseline: 1.7041x; 1.2890x over previous
//
#include <hip/hip_runtime.h>
#include <math.h>

// Problem constants (match reference module constants)
constexpr int D_MODEL  = 256;
constexpr int N_HEADS  = 8;
constexpr int N_LEVELS = 4;
constexpr int N_POINTS = 4;
constexpr int HEAD_DIM = 32;

__device__ __constant__ int c_H[4]     = {96, 48, 24, 12};
__device__ __constant__ int c_W[4]     = {96, 48, 24, 12};

// ---------------------------------------------------------------------------
// Tiled f32 GEMM: C[M,N] = A[M,256] * B[256,N] (+ bias), with fused epilogues.
// OFFATTN=true : B is split {W_off (cols 0..255, ld=256) | W_attn (cols 256..383, ld=128)}
//                epilogue: loc = ref + (off+b)/norm  -> out0[q*256 + c]
//                          attn = softmax16(score+b) -> out1[q*128 + c']
// OFFATTN=false: B = W_out (ld=256); epilogue: out0 = acc + b_out
// Tile: BM=64, BN=64, BK=16; 256 threads, each computes 4x4.
// ---------------------------------------------------------------------------
template <bool OFFATTN>
__global__ __launch_bounds__(256) void gemm_fused(
    const float* __restrict__ A,
    const float* __restrict__ Wa,
    const float* __restrict__ Wb,
    const float* __restrict__ ba,
    const float* __restrict__ bb,
    const float* __restrict__ refpts,
    float* __restrict__ out0,
    float* __restrict__ out1,
    int M)
{
    __shared__ float As[16][64];
    __shared__ float Bs[16][64];

    const int tid = threadIdx.x;
    const int m0  = blockIdx.y * 64;
    const int n0  = blockIdx.x * 64;

    const int ai = tid >> 2;          // 0..63 (row in tile)
    const int aj = (tid & 3) * 4;     // 0,4,8,12 (k offset)
    const int bi = tid >> 4;          // 0..15 (k row)
    const int bj = (tid & 15) * 4;    // 0..60 (col offset)

    const float* Bptr;
    int ldb, coff;
    if (OFFATTN && n0 >= 256) { Bptr = Wb; ldb = 128; coff = n0 - 256; }
    else                      { Bptr = Wa; ldb = 256; coff = n0; }

    const int tm = (tid >> 4) * 4;    // output row base 0..60
    const int tn = (tid & 15) * 4;    // output col base 0..60

    float acc[4][4] = {};

    for (int k0 = 0; k0 < 256; k0 += 16) {
        float4 av = make_float4(0.f, 0.f, 0.f, 0.f);
        if (m0 + ai < M)
            av = *reinterpret_cast<const float4*>(&A[(size_t)(m0 + ai) * 256 + k0 + aj]);
        As[aj + 0][ai] = av.x;
        As[aj + 1][ai] = av.y;
        As[aj + 2][ai] = av.z;
        As[aj + 3][ai] = av.w;

        float4 bv = *reinterpret_cast<const float4*>(&Bptr[(size_t)(k0 + bi) * ldb + coff + bj]);
        *reinterpret_cast<float4*>(&Bs[bi][bj]) = bv;

        __syncthreads();
#pragma unroll
        for (int kk = 0; kk < 16; ++kk) {
            float4 a4 = *reinterpret_cast<const float4*>(&As[kk][tm]);
            float4 b4 = *reinterpret_cast<const float4*>(&Bs[kk][tn]);
            float av_[4] = {a4.x, a4.y, a4.z, a4.w};
            float bv_[4] = {b4.x, b4.y, b4.z, b4.w};
#pragma unroll
            for (int i = 0; i < 4; ++i)
#pragma unroll
                for (int j = 0; j < 4; ++j)
                    acc[i][j] = fmaf(av_[i], bv_[j], acc[i][j]);
        }
        __syncthreads();
    }

    if constexpr (!OFFATTN) {
#pragma unroll
        for (int i = 0; i < 4; ++i) {
            int q = m0 + tm + i;
            if (q >= M) continue;
            float4 v;
            v.x = acc[i][0] + ba[n0 + tn + 0];
            v.y = acc[i][1] + ba[n0 + tn + 1];
            v.z = acc[i][2] + ba[n0 + tn + 2];
            v.w = acc[i][3] + ba[n0 + tn + 3];
            *reinterpret_cast<float4*>(&out0[(size_t)q * 256 + n0 + tn]) = v;
        }
    } else {
        if (n0 < 256) {
#pragma unroll
            for (int i = 0; i < 4; ++i) {
                int q = m0 + tm + i;
                if (q >= M) continue;
                float rx = refpts[q * 2 + 0];
                float ry = refpts[q * 2 + 1];
                float tmp[4];
#pragma unroll
                for (int j = 0; j < 4; ++j) {
                    int c = n0 + tn + j;          // c = h*32 + l*8 + p*2 + xy
                    float val = acc[i][j] + ba[c];
                    int xy = c & 1;
                    int l  = (c >> 3) & 3;
                    float norm = xy ? (float)c_H[l] : (float)c_W[l];
                    tmp[j] = (xy ? ry : rx) + val / norm;
                }
                float4 v = make_float4(tmp[0], tmp[1], tmp[2], tmp[3]);
                *reinterpret_cast<float4*>(&out0[(size_t)q * 256 + n0 + tn]) = v;
            }
        } else {
            __shared__ float Stile[64][65];
#pragma unroll
            for (int i = 0; i < 4; ++i)
#pragma unroll
                for (int j = 0; j < 4; ++j) {
                    int c = n0 + tn + j - 256;
                    Stile[tm + i][tn + j] = acc[i][j] + bb[c];
                }
            __syncthreads();

            int ql = tid & 63;
            int hh = tid >> 6;
            int q  = m0 + ql;
            if (q < M) {
                float s[16];
                float mx = -1e30f;
#pragma unroll
                for (int i = 0; i < 16; ++i) {
                    s[i] = Stile[ql][hh * 16 + i];
                    mx = fmaxf(mx, s[i]);
                }
                float sum = 0.f;
#pragma unroll
                for (int i = 0; i < 16; ++i) {
                    s[i] = __expf(s[i] - mx);
                    sum += s[i];
                }
                float inv = 1.0f / sum;
                int cbase = (n0 - 256) + hh * 16;
#pragma unroll
                for (int i = 0; i < 16; ++i)
                    out1[(size_t)q * 128 + cbase + i] = s[i] * inv;
            }
        }
    }
}

// ---------------------------------------------------------------------------
// Deformable bilinear sampling, float4-vectorized over dims.
// 8 lanes per (q,h) unit; lane owns 4 dims (float4).
// Per-LEVEL loop (#pragma unroll 1) to keep VGPR < 128 -> 4 waves/SIMD.
// Branchless corners: clamp indices, always load, fold validity+attn weight.
// ---------------------------------------------------------------------------
__global__ __launch_bounds__(256, 4) void sample_kernel(
    const float* __restrict__ loc,
    const float* __restrict__ attn,
    const float* __restrict__ value,   // input_flatten, [Len, 256]
    float* __restrict__ core,
    int M)
{
    const int unit = blockIdx.x * 32 + (threadIdx.x >> 3);  // (q,h)
    const int d4   = threadIdx.x & 7;                        // float4 slot 0..7
    const int q    = unit >> 3;
    const int h    = unit & 7;
    if (q >= M) return;

    const float4* locq4 = reinterpret_cast<const float4*>(loc  + (size_t)q * 256 + h * 32);
    const float4* attq4 = reinterpret_cast<const float4*>(attn + (size_t)q * 128 + h * 16);
    const float*  vbase = value + h * 32 + d4 * 4;

    float4 acc = make_float4(0.f, 0.f, 0.f, 0.f);

#pragma unroll 1
    for (int l = 0; l < 4; ++l) {
        const int Wl = 96 >> l;                       // H == W per level
        const int start = 12288 - (12288 >> (2 * l)); // 0, 9216, 11520, 12096
        const float fW = (float)Wl;
        const int rowstride = Wl * 256;
        const float* feat = vbase + (size_t)start * 256;

        float4 lp0 = locq4[l * 2 + 0];   // p0.x p0.y p1.x p1.y
        float4 lp1 = locq4[l * 2 + 1];   // p2.x p2.y p3.x p3.y
        float4 aw  = attq4[l];           // w0 w1 w2 w3

        const float lxs[4] = {lp0.x, lp0.z, lp1.x, lp1.z};
        const float lys[4] = {lp0.y, lp0.w, lp1.y, lp1.w};
        const float aws[4] = {aw.x, aw.y, aw.z, aw.w};

#pragma unroll
        for (int p = 0; p < 4; ++p) {
            float x = lxs[p] * fW - 0.5f;
            float y = lys[p] * fW - 0.5f;
            float w = aws[p];

            float x0f = floorf(x);
            float y0f = floorf(y);
            float wx1 = x - x0f, wy1 = y - y0f;
            float wx0 = 1.f - wx1, wy0 = 1.f - wy1;
            int ix = (int)x0f;
            int iy = (int)y0f;

            // validity folded into weights (branchless)
            float wxv0 = ((unsigned)ix       < (unsigned)Wl) ? wx0 : 0.f;
            float wxv1 = ((unsigned)(ix + 1) < (unsigned)Wl) ? wx1 : 0.f;
            float wyv0 = (((unsigned)iy       < (unsigned)Wl) ? wy0 : 0.f) * w;
            float wyv1 = (((unsigned)(iy + 1) < (unsigned)Wl) ? wy1 : 0.f) * w;

            // clamped indices (always-valid addresses)
            int ix0 = min(max(ix,     0), Wl - 1);
            int ix1 = min(max(ix + 1, 0), Wl - 1);
            int iy0 = min(max(iy,     0), Wl - 1);
            int iy1 = min(max(iy + 1, 0), Wl - 1);

            const float* row0 = feat + (size_t)iy0 * rowstride;
            const float* row1 = feat + (size_t)iy1 * rowstride;
            float4 v00 = *reinterpret_cast<const float4*>(&row0[(size_t)ix0 * 256]);
            float4 v10 = *reinterpret_cast<const float4*>(&row0[(size_t)ix1 * 256]);
            float4 v01 = *reinterpret_cast<const float4*>(&row1[(size_t)ix0 * 256]);
            float4 v11 = *reinterpret_cast<const float4*>(&row1[(size_t)ix1 * 256]);

            float w00 = wxv0 * wyv0, w10 = wxv1 * wyv0;
            float w01 = wxv0 * wyv1, w11 = wxv1 * wyv1;

            acc.x = fmaf(v00.x, w00, acc.x); acc.x = fmaf(v10.x, w10, acc.x);
            acc.x = fmaf(v01.x, w01, acc.x); acc.x = fmaf(v11.x, w11, acc.x);
            acc.y = fmaf(v00.y, w00, acc.y); acc.y = fmaf(v10.y, w10, acc.y);
            acc.y = fmaf(v01.y, w01, acc.y); acc.y = fmaf(v11.y, w11, acc.y);
            acc.z = fmaf(v00.z, w00, acc.z); acc.z = fmaf(v10.z, w10, acc.z);
            acc.z = fmaf(v01.z, w01, acc.z); acc.z = fmaf(v11.z, w11, acc.z);
            acc.w = fmaf(v00.w, w00, acc.w); acc.w = fmaf(v10.w, w10, acc.w);
            acc.w = fmaf(v01.w, w01, acc.w); acc.w = fmaf(v11.w, w11, acc.w);
        }
    }
    *reinterpret_cast<float4*>(&core[(size_t)q * 256 + h * 32 + d4 * 4]) = acc;
}

// ---------------------------------------------------------------------------
extern "C" void kernel_launch(void* const* d_in, const int* in_sizes, int n_in,
                              void* d_out, int out_size, void* d_ws, size_t ws_size,
                              hipStream_t stream)
{
    const float* query  = (const float*)d_in[0];
    const float* refp   = (const float*)d_in[1];
    const float* value  = (const float*)d_in[2];
    const float* W_off  = (const float*)d_in[5];
    const float* b_off  = (const float*)d_in[6];
    const float* W_attn = (const float*)d_in[7];
    const float* b_attn = (const float*)d_in[8];
    const float* W_out  = (const float*)d_in[9];
    const float* b_out  = (const float*)d_in[10];
    float* out = (float*)d_out;

    const int M = in_sizes[0] / D_MODEL;   // 12240

    float* loc  = (float*)d_ws;                      // M*256 floats
    float* attn = loc  + (size_t)M * 256;            // M*128 floats
    float* core = attn + (size_t)M * 128;            // M*256 floats

    dim3 blk(256);

    dim3 g1(6, (M + 63) / 64);
    hipLaunchKernelGGL((gemm_fused<true>), g1, blk, 0, stream,
                       query, W_off, W_attn, b_off, b_attn, refp, loc, attn, M);

    const int units = M * N_HEADS;
    dim3 g2((units + 31) / 32);
    hipLaunchKernelGGL(sample_kernel, g2, blk, 0, stream, loc, attn, value, core, M);

    dim3 g3(4, (M + 63) / 64);
    hipLaunchKernelGGL((gemm_fused<false>), g3, blk, 0, stream,
                       core, W_out, nullptr, b_out, nullptr, nullptr, out, nullptr, M);
}

// Round 4
// 73.574 us; speedup vs baseline: 2.5963x; 1.5236x over previous
//
#include <hip/hip_runtime.h>
#include <hip/hip_bf16.h>
#include <math.h>

constexpr int D_MODEL  = 256;
constexpr int N_HEADS  = 8;

typedef __attribute__((ext_vector_type(8))) short bf16x8;
typedef __attribute__((ext_vector_type(4))) float f32x4;

__device__ __forceinline__ void gld_lds16(const void* gsrc, void* ldst) {
    __builtin_amdgcn_global_load_lds(
        (const __attribute__((address_space(1))) unsigned int*)gsrc,
        (__attribute__((address_space(3))) unsigned int*)ldst, 16, 0, 0);
}

// ---------------------------------------------------------------------------
// Convert query -> bf16 [M][256]; pack W_off|W_attn|W_out transposed into
// Wt[640][256] bf16 (row c = weight column, contiguous k) so GEMM B-tiles are
// 16B-contiguous for global_load_lds.
// ---------------------------------------------------------------------------
__global__ __launch_bounds__(256) void convert_kernel(
    const float* __restrict__ q,
    const float* __restrict__ Woff,
    const float* __restrict__ Wattn,
    const float* __restrict__ Wout,
    __hip_bfloat16* __restrict__ qbf,
    __hip_bfloat16* __restrict__ wt,
    int M)
{
    int t = blockIdx.x * 256 + threadIdx.x;
    int nq4 = M * 64;                       // float4 count of query
    if (t < nq4) {
        float4 v = reinterpret_cast<const float4*>(q)[t];
        union { __hip_bfloat16 h[4]; ushort4 u; } cv;
        cv.h[0] = __float2bfloat16(v.x);
        cv.h[1] = __float2bfloat16(v.y);
        cv.h[2] = __float2bfloat16(v.z);
        cv.h[3] = __float2bfloat16(v.w);
        reinterpret_cast<ushort4*>(qbf)[t] = cv.u;
    } else {
        int t2 = t - nq4;
        if (t2 < 640 * 256) {
            int c = t2 >> 8, k = t2 & 255;
            float val = (c < 256) ? Woff[k * 256 + c]
                      : (c < 384) ? Wattn[k * 128 + (c - 256)]
                                  : Wout[k * 256 + (c - 384)];
            wt[c * 256 + k] = __float2bfloat16(val);
        }
    }
}

// ---------------------------------------------------------------------------
// bf16 MFMA GEMM: C[M,64-block] = Abf[M,256] @ Wt[wrow0+n0 .. +64][256]^T
// BM=128, BN=64, BK=64, 4 waves; 16x16x32 bf16 MFMA; per-wave 32x64 subtile.
// global_load_lds(16B) staging with row-XOR swizzle on global source,
// swizzled ds_read_b128 on the read side (rule #21 both-sides swizzle).
// EPI=0: out0 = acc + ba (f32).   EPI=1: n0<256 -> loc epilogue; else softmax.
// ---------------------------------------------------------------------------
template <int EPI>
__global__ __launch_bounds__(256) void gemm_mfma(
    const __hip_bfloat16* __restrict__ Abf,
    const __hip_bfloat16* __restrict__ Wt,
    int wrow0,
    const float* __restrict__ ba,
    const float* __restrict__ bb,
    const float* __restrict__ refpts,
    float* __restrict__ out0,
    float* __restrict__ out1,
    int M)
{
    __shared__ __align__(16) char smem[128 * 68 * 4];   // 34816B
    char*  A_lds = smem;            // [128 rows][128B]  (16KB)
    char*  B_lds = smem + 16384;    // [64 rows][128B]   (8KB)
    float* C_lds = (float*)smem;    // [128][68] f32 (unioned, used post-loop)

    const int tid = threadIdx.x;
    const int w = tid >> 6, l = tid & 63;
    const int m0 = blockIdx.y * 128;
    const int n0 = blockIdx.x * 64;

    const char* Asrc = (const char*)Abf;                                  // 512B rows
    const char* Wsrc = (const char*)(Wt + (size_t)(wrow0 + n0) * 256);    // 512B rows

    f32x4 acc[2][4] = {};

    const int lr8 = l >> 3, l7 = l & 7;

    for (int k0 = 0; k0 < 512; k0 += 128) {   // K bytes per row step (64 bf16)
        // ---- stage A: 16KB, 4 issues/wave (1KB each = 8 rows) ----
#pragma unroll
        for (int i = 0; i < 4; ++i) {
            int chunk = (w << 2) + i;            // 0..15
            int row = (chunk << 3) + lr8;        // 0..127
            int m = m0 + row; m = m < M ? m : (M - 1);
            gld_lds16(Asrc + (size_t)m * 512 + k0 + ((l7 ^ (row & 7)) << 4),
                      A_lds + (chunk << 10));
        }
        // ---- stage B: 8KB, 2 issues/wave ----
#pragma unroll
        for (int i = 0; i < 2; ++i) {
            int chunk = (w << 1) + i;            // 0..7
            int row = (chunk << 3) + lr8;        // 0..63
            gld_lds16(Wsrc + (size_t)row * 512 + k0 + ((l7 ^ (row & 7)) << 4),
                      B_lds + (chunk << 10));
        }
        __syncthreads();   // compiler drains vmcnt before barrier

#pragma unroll
        for (int kk = 0; kk < 2; ++kk) {
            bf16x8 av[2], bv[4];
#pragma unroll
            for (int mf = 0; mf < 2; ++mf) {
                int arow = (w << 5) + (mf << 4) + (l & 15);
                int acb = ((kk << 6) + ((l >> 4) << 4)) ^ ((arow & 7) << 4);
                av[mf] = *(const bf16x8*)(A_lds + arow * 128 + acb);
            }
#pragma unroll
            for (int nf = 0; nf < 4; ++nf) {
                int brow = (nf << 4) + (l & 15);
                int bcb = ((kk << 6) + ((l >> 4) << 4)) ^ ((brow & 7) << 4);
                bv[nf] = *(const bf16x8*)(B_lds + brow * 128 + bcb);
            }
#pragma unroll
            for (int mf = 0; mf < 2; ++mf)
#pragma unroll
                for (int nf = 0; nf < 4; ++nf)
                    acc[mf][nf] = __builtin_amdgcn_mfma_f32_16x16x32_bf16(
                        av[mf], bv[nf], acc[mf][nf], 0, 0, 0);
        }
        __syncthreads();
    }

    // ---- dump accumulators to C_lds (f32, pad 68 to break bank stride) ----
#pragma unroll
    for (int mf = 0; mf < 2; ++mf)
#pragma unroll
        for (int nf = 0; nf < 4; ++nf) {
            int col = (nf << 4) + (l & 15);
            int rbase = (w << 5) + (mf << 4) + ((l >> 4) << 2);
#pragma unroll
            for (int j = 0; j < 4; ++j)
                C_lds[(rbase + j) * 68 + col] = acc[mf][nf][j];
        }
    __syncthreads();

    if (EPI == 0 || n0 < 256) {
        // linear epilogue: +bias, optional loc transform; 64B coalesced stores
#pragma unroll
        for (int r2 = 0; r2 < 2; ++r2) {
            int row = (r2 << 6) + (tid >> 2);
            int q = m0 + row;
            if (q >= M) continue;
            float rx = 0.f, ry = 0.f;
            if (EPI == 1) { rx = refpts[q * 2]; ry = refpts[q * 2 + 1]; }
#pragma unroll
            for (int g = 0; g < 4; ++g) {
                int col = ((tid & 3) << 4) + (g << 2);
                float4 v  = *(float4*)&C_lds[row * 68 + col];
                float4 b4 = *(const float4*)&ba[n0 + col];
                if (EPI == 0) {
                    v.x += b4.x; v.y += b4.y; v.z += b4.z; v.w += b4.w;
                } else {
                    int c = n0 + col;                        // h*32+l*8+p*2+xy
                    float rn = 1.0f / (float)(96 >> ((c >> 3) & 3));
                    v.x = rx + (v.x + b4.x) * rn;
                    v.y = ry + (v.y + b4.y) * rn;
                    v.z = rx + (v.z + b4.z) * rn;
                    v.w = ry + (v.w + b4.w) * rn;
                }
                *(float4*)&out0[(size_t)q * 256 + n0 + col] = v;
            }
        }
    } else {
        // softmax epilogue: 512 (row, head) units
        for (int u = tid; u < 512; u += 256) {
            int row = u >> 2, hh = u & 3;
            int q = m0 + row;
            if (q >= M) continue;
            int cg = (n0 - 256) + (hh << 4);
            float s[16];
            float mx = -1e30f;
#pragma unroll
            for (int i = 0; i < 16; ++i) {
                s[i] = C_lds[row * 68 + (hh << 4) + i] + bb[cg + i];
                mx = fmaxf(mx, s[i]);
            }
            float sum = 0.f;
#pragma unroll
            for (int i = 0; i < 16; ++i) { s[i] = __expf(s[i] - mx); sum += s[i]; }
            float inv = 1.0f / sum;
#pragma unroll
            for (int g = 0; g < 4; ++g) {
                float4 v = make_float4(s[g*4]*inv, s[g*4+1]*inv, s[g*4+2]*inv, s[g*4+3]*inv);
                *(float4*)&out1[(size_t)q * 128 + cg + (g << 2)] = v;
            }
        }
    }
}

// ---------------------------------------------------------------------------
// Deformable bilinear sampling (unchanged structure from R3), bf16 output.
// 8 lanes per (q,h) unit; lane owns 4 dims (float4). Per-level loop keeps
// VGPR < 128 -> 4 waves/SIMD. Branchless clamped corners.
// ---------------------------------------------------------------------------
__global__ __launch_bounds__(256, 4) void sample_kernel(
    const float* __restrict__ loc,
    const float* __restrict__ attn,
    const float* __restrict__ value,   // input_flatten, [Len, 256] f32
    __hip_bfloat16* __restrict__ core, // [M][256] bf16
    int M)
{
    const int unit = blockIdx.x * 32 + (threadIdx.x >> 3);  // (q,h)
    const int d4   = threadIdx.x & 7;
    const int q    = unit >> 3;
    const int h    = unit & 7;
    if (q >= M) return;

    const float4* locq4 = reinterpret_cast<const float4*>(loc  + (size_t)q * 256 + h * 32);
    const float4* attq4 = reinterpret_cast<const float4*>(attn + (size_t)q * 128 + h * 16);
    const float*  vbase = value + h * 32 + d4 * 4;

    float4 acc = make_float4(0.f, 0.f, 0.f, 0.f);

#pragma unroll 1
    for (int lvl = 0; lvl < 4; ++lvl) {
        const int Wl = 96 >> lvl;                        // H == W per level
        const int start = 12288 - (12288 >> (2 * lvl));  // 0,9216,11520,12096
        const float fW = (float)Wl;
        const int rowstride = Wl * 256;
        const float* feat = vbase + (size_t)start * 256;

        float4 lp0 = locq4[lvl * 2 + 0];
        float4 lp1 = locq4[lvl * 2 + 1];
        float4 aw  = attq4[lvl];

        const float lxs[4] = {lp0.x, lp0.z, lp1.x, lp1.z};
        const float lys[4] = {lp0.y, lp0.w, lp1.y, lp1.w};
        const float aws[4] = {aw.x, aw.y, aw.z, aw.w};

#pragma unroll
        for (int p = 0; p < 4; ++p) {
            float x = lxs[p] * fW - 0.5f;
            float y = lys[p] * fW - 0.5f;
            float wgt = aws[p];

            float x0f = floorf(x);
            float y0f = floorf(y);
            float wx1 = x - x0f, wy1 = y - y0f;
            float wx0 = 1.f - wx1, wy0 = 1.f - wy1;
            int ix = (int)x0f;
            int iy = (int)y0f;

            float wxv0 = ((unsigned)ix       < (unsigned)Wl) ? wx0 : 0.f;
            float wxv1 = ((unsigned)(ix + 1) < (unsigned)Wl) ? wx1 : 0.f;
            float wyv0 = (((unsigned)iy       < (unsigned)Wl) ? wy0 : 0.f) * wgt;
            float wyv1 = (((unsigned)(iy + 1) < (unsigned)Wl) ? wy1 : 0.f) * wgt;

            int ix0 = min(max(ix,     0), Wl - 1);
            int ix1 = min(max(ix + 1, 0), Wl - 1);
            int iy0 = min(max(iy,     0), Wl - 1);
            int iy1 = min(max(iy + 1, 0), Wl - 1);

            const float* row0 = feat + (size_t)iy0 * rowstride;
            const float* row1 = feat + (size_t)iy1 * rowstride;
            float4 v00 = *reinterpret_cast<const float4*>(&row0[(size_t)ix0 * 256]);
            float4 v10 = *reinterpret_cast<const float4*>(&row0[(size_t)ix1 * 256]);
            float4 v01 = *reinterpret_cast<const float4*>(&row1[(size_t)ix0 * 256]);
            float4 v11 = *reinterpret_cast<const float4*>(&row1[(size_t)ix1 * 256]);

            float w00 = wxv0 * wyv0, w10 = wxv1 * wyv0;
            float w01 = wxv0 * wyv1, w11 = wxv1 * wyv1;

            acc.x = fmaf(v00.x, w00, acc.x); acc.x = fmaf(v10.x, w10, acc.x);
            acc.x = fmaf(v01.x, w01, acc.x); acc.x = fmaf(v11.x, w11, acc.x);
            acc.y = fmaf(v00.y, w00, acc.y); acc.y = fmaf(v10.y, w10, acc.y);
            acc.y = fmaf(v01.y, w01, acc.y); acc.y = fmaf(v11.y, w11, acc.y);
            acc.z = fmaf(v00.z, w00, acc.z); acc.z = fmaf(v10.z, w10, acc.z);
            acc.z = fmaf(v01.z, w01, acc.z); acc.z = fmaf(v11.z, w11, acc.z);
            acc.w = fmaf(v00.w, w00, acc.w); acc.w = fmaf(v10.w, w10, acc.w);
            acc.w = fmaf(v01.w, w01, acc.w); acc.w = fmaf(v11.w, w11, acc.w);
        }
    }

    union { __hip_bfloat16 h4[4]; ushort4 u4; } st;
    st.h4[0] = __float2bfloat16(acc.x);
    st.h4[1] = __float2bfloat16(acc.y);
    st.h4[2] = __float2bfloat16(acc.z);
    st.h4[3] = __float2bfloat16(acc.w);
    *reinterpret_cast<ushort4*>(core + ((size_t)q * 256 + h * 32 + d4 * 4)) = st.u4;
}

// ---------------------------------------------------------------------------
extern "C" void kernel_launch(void* const* d_in, const int* in_sizes, int n_in,
                              void* d_out, int out_size, void* d_ws, size_t ws_size,
                              hipStream_t stream)
{
    const float* query  = (const float*)d_in[0];
    const float* refp   = (const float*)d_in[1];
    const float* value  = (const float*)d_in[2];
    const float* W_off  = (const float*)d_in[5];
    const float* b_off  = (const float*)d_in[6];
    const float* W_attn = (const float*)d_in[7];
    const float* b_attn = (const float*)d_in[8];
    const float* W_out  = (const float*)d_in[9];
    const float* b_out  = (const float*)d_in[10];
    float* out = (float*)d_out;

    const int M = in_sizes[0] / D_MODEL;   // 12240

    // workspace layout (~25.4 MB)
    float* loc  = (float*)d_ws;                                   // M*256 f32
    float* attn = loc + (size_t)M * 256;                          // M*128 f32
    __hip_bfloat16* qbf = (__hip_bfloat16*)(attn + (size_t)M * 128); // M*256 bf16
    __hip_bfloat16* wt  = qbf + (size_t)M * 256;                  // 640*256 bf16
    __hip_bfloat16* core = qbf;   // alias: qbf dead after stage 1

    dim3 blk(256);
    const int mblocks = (M + 127) / 128;

    // Stage 0: f32 -> bf16 conversion + weight pack/transpose
    int convthreads = M * 64 + 640 * 256;
    hipLaunchKernelGGL(convert_kernel, dim3((convthreads + 255) / 256), blk, 0, stream,
                       query, W_off, W_attn, W_out, qbf, wt, M);

    // Stage 1: offsets+attention GEMM (N=384) with loc/softmax epilogue
    hipLaunchKernelGGL((gemm_mfma<1>), dim3(6, mblocks), blk, 0, stream,
                       qbf, wt, 0, b_off, b_attn, refp, loc, attn, M);

    // Stage 2: deformable bilinear sampling -> core (bf16, overwrites qbf)
    const int units = M * N_HEADS;
    hipLaunchKernelGGL(sample_kernel, dim3((units + 31) / 32), blk, 0, stream,
                       loc, attn, value, core, M);

    // Stage 3: output projection (N=256)
    hipLaunchKernelGGL((gemm_mfma<0>), dim3(4, mblocks), blk, 0, stream,
                       core, wt, 384, b_out, nullptr, nullptr, out, nullptr, M);
}